// Round 6
// baseline (1889.646 us; speedup 1.0000x reference)
//
#include <hip/hip_runtime.h>

// samx_qkv_1bit R17: R16 two-wave split + wave0 prediction/prefetch.
// R16 (1543us): wall = max(key_p1, query) + key_p2 + 2 barriers. Query leg
// ~2-3 dependent loads; key_p1 (gather -> ballot -> readlane -> rec[d] ->
// clone/permute/fresh-stores) is the longer leg. R17 takes key_p1 off the
// critical path with R14's (verified-correct) prediction, now correctly
// scheduled by construction:
//   - tail-gather prefetch: wave0 issues reca[cid] at end of p2 (after the
//     lgkmcnt(0) drain, before barrier B); same-wave DS order => sees all
//     step-i stores; latency hides under barrier sync + next query.
//   - t2==1 prediction: img[0]=tk[j_prev]=-1 always (fresh state gets
//     transitions only from later steps' prefix stores), so t2==1 iff
//     tr[flj][ks']!=-1, register-computable from pf1n = post-step rec[flj]
//     (clone record / patched rec[d] / register-tracked rec0). Hit: skip
//     brkmask/ctz/readlanes/rec[d] load (d,mlp,recd register-known,
//     reca[nx1] prefetched). Miss or stale (-1 vs j, the only possible
//     staleness) -> generic path; never a wrong hit.
// Fallback/overflow steps disable prediction (have_pf1=false, rec0 resync);
// cold path R10-verified verbatim in wave0's exclusive phase2.

#define NSTATES 4096
#define TLEN 2048

typedef unsigned long long u64m;

__device__ __forceinline__ int f_tr(u64m r, int s) {   // transition by symbol
  return (int)(short)(unsigned short)(r >> (s << 4));
}
__device__ __forceinline__ int f_fl(u64m r) {          // suffix link
  return (int)(short)(unsigned short)(r >> 32);
}
__device__ __forceinline__ int f_ml(u64m r) {          // max length
  return (int)(r >> 48);
}
__device__ __forceinline__ u64m set_tr(u64m r, int s, int v) {
  const int sh = s << 4;
  return (r & ~(0xFFFFull << sh)) | ((u64m)(unsigned short)v << sh);
}

// img[lane-1] without DS: DPP row_shr:1 + patch row-boundary lanes 16/32/48.
// Lane 0 result is don't-care (rs requires lane >= t2 >= 1).
__device__ __forceinline__ int lane_shr1(int v, int lane) {
  int sh = __builtin_amdgcn_update_dpp(0, v, 0x111 /*row_shr:1*/, 0xF, 0xF, true);
  const int v15 = __builtin_amdgcn_readlane(v, 15);
  const int v31 = __builtin_amdgcn_readlane(v, 31);
  const int v47 = __builtin_amdgcn_readlane(v, 47);
  if (lane == 16) sh = v15;
  if (lane == 32) sh = v31;
  if (lane == 48) sh = v47;
  return sh;
}

__global__ __launch_bounds__(128)
void samx_main(const float* __restrict__ q,
               const float* __restrict__ k,
               unsigned* __restrict__ outpos,
               int T, int C) {
  __shared__ u64m           reca[NSTATES];  // tr0[15:0] tr1[31:16] fl[47:32] ml[63:48]
  __shared__ unsigned short rla[NSTATES];   // last end pos, 0xFFFF = -1

  unsigned short* recw = (unsigned short*)reca;  // [4*s + f]: f=0 tr0,1 tr1,2 fl,3 ml
  unsigned*       rech = (unsigned*)reca;        // [2*s+1] = fl|ml<<16

  const int row = blockIdx.x;
  const int b = row / C;
  const int c = row - b * C;
  const int lane = threadIdx.x & 63;
  const int wid = threadIdx.x >> 6;   // 0 = key wave, 1 = query wave

  for (int s = threadIdx.x; s < NSTATES; s += 128) {
    reca[s] = 0x0000FFFFFFFFFFFFull;  // tr0=tr1=fl=-1, ml=0
    rla[s] = 0xFFFFu;
  }

  const size_t rowbase = (size_t)b * (size_t)T * (size_t)C + (size_t)c;
  unsigned* outr = outpos + rowbase;

  // Binarize only the stream this wave consumes: wave0 -> k, wave1 -> q.
  const float* src = (wid == 0 ? k : q) + rowbase;
  unsigned bits = 0u;
  {
    const int t0 = lane * 32;
#pragma unroll 8
    for (int jj = 0; jj < 32; ++jj) {
      if (src[(size_t)(t0 + jj) * C] > 0.0f) bits |= (1u << jj);
    }
  }
  __syncthreads();

  // ---- wave0 state ----
  int cid = 0;                  // my chain slot's state id (slot = lane)
  bool cval = (lane == 0);      // slot validity (valid slots contiguous)
  bool trunc = false;
  int g = 0;    // last state (uniform; used by fallback)
  int mlg = 0;  // ml[g]
  int u = 1;    // next free state id
  u64m rec0 = 0x0000FFFFFFFFFFFFull;  // register image of reca[0]
  u64m pf_rec = reca[0];   // prefetched reca[cid]
  u64m pf1c = 0;           // pf1n of previous step (rec[flj'] post-step)
  u64m pf_recd = 0;        // prefetched reca[nx1]
  int  nx1 = -1;           // predicted img[1] (t2==1 iff >= 0)
  bool have_pf1 = false;
  // ---- wave1 state ----
  int w = 0;    // query-match state
  int h = 0;    // query-match length

  int sym = (int)(__builtin_amdgcn_readlane((int)bits, 0) & 1);  // ks / qs

  for (int i = 0; i < T; ++i) {
    const bool hot = !trunc;
    const int j = u++;          // wave1's copies of u/j are unused
    const int mlj = mlg + 1;

    // phase1 -> phase2 carriers (wave0)
    int d = -1, bb = -1, flj = 0, ndd = 0, newlen = 2, pushed = 0;
    bool prefl = false, inrun = false, nobrk = false;
    u64m pf1pre = 0;

    if (wid == 0) {
      // ================= PHASE 1 — KEY (reads + fresh stores) =============
      if (hot) {
        const int ks = sym;
        const u64m rk = pf_rec;                    // prefetched gather
        const int img = f_tr(rk, ks);
        int t2, mlp;
        u64m recd;
        if (nx1 >= 0) {
          // FAST: img[0]==-1 invariant + img[1]=nx1!=-1 => t2==1 exactly
          t2 = 1; d = nx1; mlp = f_ml(pf1c); recd = pf_recd;
        } else {
          const int myml = f_ml(rk);
          const u64m brkmask = __ballot(cval && img != -1);
          nobrk = (brkmask == 0);
          t2 = nobrk ? 64 : (int)__builtin_ctzll(brkmask);
          const int t2c = (t2 > 63) ? 63 : t2;
          d = __builtin_amdgcn_readlane(img, t2c);
          mlp = __builtin_amdgcn_readlane(myml, t2c);
          recd = reca[d < 0 ? 0 : d];              // ONE b64 for d
        }
        prefl = cval && (lane < t2);

        // permute machinery (img-only; overlaps clone work)
        const int previmg = lane_shr1(img, lane);
        const bool rs = cval && lane >= t2 && (lane == t2 || img != previmg);
        const u64m rsmask = __ballot(rs);
        ndd = (int)__builtin_popcountll(rsmask);
        newlen = ndd + 2;  // [j] + ndd images + [root]
        const unsigned below =
            __builtin_amdgcn_mbcnt_hi((unsigned)(rsmask >> 32),
                __builtin_amdgcn_mbcnt_lo((unsigned)rsmask, 0u));
        const int dst = rs ? ((int)below + 1) : 0; // trash -> slot 0
        pushed = __builtin_amdgcn_ds_permute(dst << 2, img);

        // clone decision + fresh-state stores (invisible to wave1: nothing
        // links to j/bb until phase2)
        int dtr0 = f_tr(recd, 0);
        int dtr1 = f_tr(recd, 1);
        const unsigned fmdhi = (unsigned)(recd >> 32);  // fl|ml of d
        if (!nobrk) {
          const int mld = (int)(fmdhi >> 16);
          if (mlp + 1 == mld) {
            flj = d;
            // unpatched: only possible staleness is tr[d][ks] -1 -> j,
            // which turns next-step prediction into a conservative miss
            pf1pre = (u64m)(unsigned short)dtr0
                   | ((u64m)(unsigned short)dtr1 << 16)
                   | ((u64m)(fmdhi & 0xFFFFu) << 32)
                   | ((u64m)(unsigned)mld << 48);
          } else {
            bb = u++;  // clone of d with length mlp+1
            // patch phase2 prefix-store effect on tk[d] (d may be pre-t2 node)
            const u64m pb = __ballot(prefl && cid == d);
            if (pb != 0ull) { if (ks) dtr1 = j; else dtr0 = j; }
            pf1pre = (u64m)(unsigned short)dtr0
                   | ((u64m)(unsigned short)dtr1 << 16)
                   | ((u64m)(fmdhi & 0xFFFFu) << 32)
                   | ((u64m)(unsigned)(mlp + 1) << 48);
            if (lane == 0) {
              // rl[bb] copy elided: bb is slot 1 of new chain -> stamped i
              reca[bb] = pf1pre;
            }
            flj = bb;
          }
        }
        if (lane == 0)
          rech[2 * j + 1] = (unsigned)(flj & 0xFFFF) | ((unsigned)mlj << 16);

        if (bb >= 0) {  // redirect run: contiguous img==d from t2
          const u64m eq = __ballot(cval && img == d) >> t2;
          const int runlen = (eq == ~0ull) ? 64 : (int)__builtin_ctzll(~eq);
          inrun = cval && lane >= t2 && lane < t2 + runlen;
        }
      }
    } else {
      // ================= PHASE 1 — QUERY (reads only; sees post-(i-1)) ====
      const int qs = sym;
      int p = w, x = h;
      {
        u64m rr = reca[w];
        for (;;) {
          const int tv = f_tr(rr, qs);
          if (tv != -1) { p = tv; x = x + 1; break; }
          const int mp = f_ml(rr);
          if (x > mp) x = mp;
          p = f_fl(rr);
          if (p == -1) { p = 0; x = 0; break; }
          rr = reca[p];   // ONE b64 per hop
        }
      }
      const u64m recP = reca[p];
      int rlv = (int)(short)rla[p];
      unsigned fmv = (unsigned)(recP >> 32);
      int vst = p;
      for (;;) {
        const int fv = (int)(short)(fmv & 0xFFFFu);
        if (fv == -1) break;
        const unsigned fmf = rech[2 * fv + 1];
        const int rlf = (int)(short)rla[fv];   // speculative, same hop
        if ((int)(fmf >> 16) < x) break;
        vst = fv; fmv = fmf; rlv = rlf;
      }
      int rv = -1;
      for (;;) {
        if (vst == -1) { rv = -1; break; }
        if ((int)(fmv >> 16) > 0 && rlv >= 0) { rv = rlv; break; }
        vst = (int)(short)(fmv & 0xFFFFu);
        if (vst == -1) { rv = -1; break; }
        fmv = rech[2 * vst + 1];
        rlv = (int)(short)rla[vst];
      }
      w = p; h = x;
      if (lane == 0) outr[(size_t)i * C] = (unsigned)(rv + 1);
    }

    asm volatile("" ::: "memory");
    __builtin_amdgcn_s_barrier();   // ---- A: query reads done ----
    asm volatile("" ::: "memory");

    u64m pf1n = 0;
    if (wid == 0) {
      // ============ PHASE 2 — KEY visible stores (exclusive) ==============
      const int ks = sym;
      if (hot) {
        if (prefl) recw[4 * cid + ks] = (unsigned short)j;
        if (inrun) recw[4 * cid + ks] = (unsigned short)bb;
        if (bb >= 0 && lane == 0) recw[4 * d + 2] = (unsigned short)bb; // fl[d]=bb

        // rec0 register maintenance + pf1n finalize
        if (nobrk) rec0 = set_tr(rec0, ks, j);
        else if (bb >= 0 && __ballot(inrun && cid == 0) != 0ull)
          rec0 = set_tr(rec0, ks, bb);
        pf1n = nobrk ? rec0 : pf1pre;

        // new chain: [j, flj, run-start images #1.., root]
        int nv = 0;  // default root/padding (safe gather next step)
        if (lane == 0) nv = j;
        else if (lane == 1) nv = flj;
        else if (lane - 1 < ndd) nv = pushed;
        const bool nval = (lane < newlen);
        if (nval) rla[nv] = (unsigned short)i;

        const bool overflow = (newlen > 64);
        if (overflow) {  // cold: stamp the unstored tail serially
          const int nv63 = __builtin_amdgcn_readlane(nv, 63);
          if (lane == 0) {
            int vp = (int)(short)(rech[2 * nv63 + 1] & 0xFFFFu);
            while (vp != -1) {
              rla[vp] = (unsigned short)i;
              vp = (int)(short)(rech[2 * vp + 1] & 0xFFFFu);
            }
          }
        }
        cid = nv; cval = nval; trunc = overflow;
        have_pf1 = !overflow;
      } else {
        // ===== COLD fallback: reference-exact serial step (R10-verified) ==
        int pcur = g, d2 = -1, idbrk = -1;
        for (;;) {
          if (pcur == -1) break;
          const u64m rr = reca[pcur];
          const int tv = f_tr(rr, ks);
          if (tv != -1) { d2 = tv; idbrk = pcur; break; }
          if (lane == 0) recw[4 * pcur + ks] = (unsigned short)j;
          pcur = f_fl(rr);
        }
        int fl2 = 0;
        if (d2 != -1) {
          const int mlp2 = f_ml(reca[idbrk]);
          const u64m rd2 = reca[d2];
          const int mld = f_ml(rd2);
          if (mlp2 + 1 == mld) {
            fl2 = d2;
          } else {
            const int bbc = u++;
            const int drl = (int)(short)rla[d2];
            if (lane == 0) {
              reca[bbc] = (u64m)(unsigned short)f_tr(rd2, 0)
                        | ((u64m)(unsigned short)f_tr(rd2, 1) << 16)
                        | ((u64m)((unsigned)(rd2 >> 32) & 0xFFFFu) << 32)
                        | ((u64m)(unsigned)(mlp2 + 1) << 48);
              rla[bbc] = (unsigned short)drl;
              recw[4 * d2 + 2] = (unsigned short)bbc;   // fl[d2] = bbc
            }
            fl2 = bbc;
            int p3 = idbrk;
            for (;;) {
              if (p3 == -1) break;
              const u64m r3 = reca[p3];
              const int tv3 = f_tr(r3, ks);
              if (tv3 != d2) break;
              if (lane == 0) recw[4 * p3 + ks] = (unsigned short)bbc;
              p3 = f_fl(r3);
            }
          }
        }
        if (lane == 0)
          rech[2 * j + 1] = (unsigned)(fl2 & 0xFFFF) | ((unsigned)mlj << 16);
        // full propagation walk; rebuild lane chain while stamping
        int vp = j, ncs = 0;
        bool tr2 = false;
        for (;;) {
          if (vp == -1) break;
          if (ncs < 64) { if (lane == ncs) cid = vp; ++ncs; }
          else tr2 = true;
          if (lane == 0) rla[vp] = (unsigned short)i;
          vp = (int)(short)(rech[2 * vp + 1] & 0xFFFFu);
        }
        cval = (lane < ncs);
        trunc = tr2;
        rec0 = reca[0];   // resync register image of root
        have_pf1 = false;
      }
      g = j; mlg = mlj;
    }
    // wave1: nothing in phase2.

    // next-step symbol (both waves, own stream)
    if (i + 1 < T) {
      const int in = i + 1;
      const unsigned bw = (unsigned)__builtin_amdgcn_readlane((int)bits, in >> 5);
      sym = (int)((bw >> (in & 31)) & 1u);
    }

    if (wid == 0) {
      // drain wave0's LDS stores so wave1's next-phase1 reads see them; then
      // issue next-step prefetches (post-drain => coherent with all step-i
      // stores; step-(i+1) fresh stores touch only j'/bb' > prefetched ids;
      // latency hides under barrier sync + next query start).
      asm volatile("s_waitcnt lgkmcnt(0)" ::: "memory");
      if (i + 1 < T) {
        pf_rec = reca[cid];
        nx1 = have_pf1 ? f_tr(pf1n, sym) : -1;   // sym already = ks(i+1)
        pf_recd = reca[nx1 < 0 ? 0 : nx1];
        pf1c = pf1n;
      }
    }
    __builtin_amdgcn_s_barrier();   // ---- B: automaton post-i published ----
    asm volatile("" ::: "memory");
  }
}

// Fully parallel epilogue: vidx (u32, = r+1, 0 = no match) -> sign*e.
__global__ __launch_bounds__(256)
void samx_epilogue(const float* __restrict__ v,
                   const float* __restrict__ e,
                   unsigned* __restrict__ out,
                   int T, int C, int total) {
  const int idx = blockIdx.x * 256 + threadIdx.x;
  if (idx >= total) return;
  const unsigned vidx = out[idx];
  const int c = idx % C;
  const int bi = idx / C;
  const int b = bi / T;
  const float ev = e[c];
  float val = -ev;  // y=0
  if (vidx != 0u) {
    if (v[((size_t)b * (size_t)T + (size_t)vidx) * (size_t)C + (size_t)c] > 0.0f)
      val = ev;
  }
  out[idx] = __float_as_uint(val);
}

extern "C" void kernel_launch(void* const* d_in, const int* in_sizes, int n_in,
                              void* d_out, int out_size, void* d_ws, size_t ws_size,
                              hipStream_t stream) {
  const float* q = (const float*)d_in[0];
  const float* k = (const float*)d_in[1];
  const float* v = (const float*)d_in[2];
  const float* e = (const float*)d_in[3];

  const int C = in_sizes[3];
  const int T = TLEN;
  const int B = in_sizes[0] / (T * C);
  const int total = out_size;

  samx_main<<<dim3(B * C), dim3(128), 0, stream>>>(q, k, (unsigned*)d_out, T, C);
  samx_epilogue<<<dim3((total + 255) / 256), dim3(256), 0, stream>>>(
      v, e, (unsigned*)d_out, T, C, total);
}

// Round 7
// 1582.878 us; speedup vs baseline: 1.1938x; 1.1938x over previous
//
#include <hip/hip_runtime.h>

// samx_qkv_1bit R18: R16 skeleton (verbatim) + wave1 speculative first-hop.
// R17 post-mortem: shaving wave0's p1 REGRESSED (1543->1870) -> p1 has slack
// (wall = query + p2 + 2 barriers); anything added between barrier A and
// barrier B lands on the fully-serialized segment. So wave0/p2/barriers are
// reverted to R16 byte-for-byte. The one change is wave1-only:
//   Speculative walk1 first hop with in-flight verification. Wave1 holds
//   rrP = reca[p] from the previous query; stale only if p2(i) stored to
//   state w (query end-state on the key chain's stored set - rare).
//   Query(i+1): issue fresh=reca[w] (verify), speculatively tv=f_tr(rrP,qs),
//   issue reca[tv]+rla[tv] now -> two serial hops collapse into one.
//   fresh==rrP (u64) confirms; mismatch redoes walk1 from fresh
//   (reference-exact; spec can never be silently wrong). Spec target tv is
//   from the post-p2(i) automaton, so it never aliases wave0's concurrent
//   p1(i+1) fresh-state writes (j'/bb' unreachable until p2(i+1)).
// Cold fallback R10-verified verbatim in wave0's exclusive phase2.

#define NSTATES 4096
#define TLEN 2048

typedef unsigned long long u64m;

__device__ __forceinline__ int f_tr(u64m r, int s) {   // transition by symbol
  return (int)(short)(unsigned short)(r >> (s << 4));
}
__device__ __forceinline__ int f_fl(u64m r) {          // suffix link
  return (int)(short)(unsigned short)(r >> 32);
}
__device__ __forceinline__ int f_ml(u64m r) {          // max length
  return (int)(r >> 48);
}

// img[lane-1] without DS: DPP row_shr:1 + patch row-boundary lanes 16/32/48.
// Lane 0 result is don't-care (rs requires lane >= t2 >= 1).
__device__ __forceinline__ int lane_shr1(int v, int lane) {
  int sh = __builtin_amdgcn_update_dpp(0, v, 0x111 /*row_shr:1*/, 0xF, 0xF, true);
  const int v15 = __builtin_amdgcn_readlane(v, 15);
  const int v31 = __builtin_amdgcn_readlane(v, 31);
  const int v47 = __builtin_amdgcn_readlane(v, 47);
  if (lane == 16) sh = v15;
  if (lane == 32) sh = v31;
  if (lane == 48) sh = v47;
  return sh;
}

__global__ __launch_bounds__(128)
void samx_main(const float* __restrict__ q,
               const float* __restrict__ k,
               unsigned* __restrict__ outpos,
               int T, int C) {
  __shared__ u64m           reca[NSTATES];  // tr0[15:0] tr1[31:16] fl[47:32] ml[63:48]
  __shared__ unsigned short rla[NSTATES];   // last end pos, 0xFFFF = -1

  unsigned short* recw = (unsigned short*)reca;  // [4*s + f]: f=0 tr0,1 tr1,2 fl,3 ml
  unsigned*       rech = (unsigned*)reca;        // [2*s+1] = fl|ml<<16

  const int row = blockIdx.x;
  const int b = row / C;
  const int c = row - b * C;
  const int lane = threadIdx.x & 63;
  const int wid = threadIdx.x >> 6;   // 0 = key wave, 1 = query wave

  for (int s = threadIdx.x; s < NSTATES; s += 128) {
    reca[s] = 0x0000FFFFFFFFFFFFull;  // tr0=tr1=fl=-1, ml=0
    rla[s] = 0xFFFFu;
  }

  const size_t rowbase = (size_t)b * (size_t)T * (size_t)C + (size_t)c;
  unsigned* outr = outpos + rowbase;

  // Binarize only the stream this wave consumes: wave0 -> k, wave1 -> q.
  // Lane L holds bits t = 32L..32L+31.
  const float* src = (wid == 0 ? k : q) + rowbase;
  unsigned bits = 0u;
  {
    const int t0 = lane * 32;
#pragma unroll 8
    for (int jj = 0; jj < 32; ++jj) {
      if (src[(size_t)(t0 + jj) * C] > 0.0f) bits |= (1u << jj);
    }
  }
  __syncthreads();

  // ---- wave0 state ----
  int cid = 0;                  // my chain slot's state id (slot = lane)
  bool cval = (lane == 0);      // slot validity (valid slots contiguous)
  bool trunc = false;
  int g = 0;    // last state (uniform; used by fallback)
  int mlg = 0;  // ml[g]
  int u = 1;    // next free state id
  // ---- wave1 state ----
  int w = 0;    // query-match state
  int h = 0;    // query-match length
  u64m rrP = reca[0];  // wave1: reca[w] as read during the previous query
                       // (possibly stale wrt the last p2 - verified each use)

  int sym = (int)(__builtin_amdgcn_readlane((int)bits, 0) & 1);  // ks / qs

  for (int i = 0; i < T; ++i) {
    const bool hot = !trunc;
    const int j = u++;          // wave1's copies of u/j are unused
    const int mlj = mlg + 1;

    // phase1 -> phase2 carriers (wave0)
    int d = -1, bb = -1, flj = 0, ndd = 0, newlen = 2, pushed = 0;
    bool prefl = false, inrun = false;

    if (wid == 0) {
      // ================= PHASE 1 — KEY (reads + fresh stores) =============
      if (hot) {
        const int ks = sym;
        const u64m rk = reca[cid];                 // gather (post-(i-1))
        const int img = f_tr(rk, ks);
        const int myml = f_ml(rk);
        const u64m brkmask = __ballot(cval && img != -1);
        const bool nobrk = (brkmask == 0);
        const int t2 = nobrk ? 64 : (int)__builtin_ctzll(brkmask);
        const int t2c = (t2 > 63) ? 63 : t2;
        d = __builtin_amdgcn_readlane(img, t2c);
        const int mlp = __builtin_amdgcn_readlane(myml, t2c);
        prefl = cval && (lane < t2);

        const u64m recd = reca[d < 0 ? 0 : d];     // ONE b64 for d

        // permute machinery (img-only; overlaps recd load)
        const int previmg = lane_shr1(img, lane);
        const bool rs = cval && lane >= t2 && (lane == t2 || img != previmg);
        const u64m rsmask = __ballot(rs);
        ndd = (int)__builtin_popcountll(rsmask);
        newlen = ndd + 2;  // [j] + ndd images + [root]
        const unsigned below =
            __builtin_amdgcn_mbcnt_hi((unsigned)(rsmask >> 32),
                __builtin_amdgcn_mbcnt_lo((unsigned)rsmask, 0u));
        const int dst = rs ? ((int)below + 1) : 0; // trash -> slot 0
        pushed = __builtin_amdgcn_ds_permute(dst << 2, img);

        // clone decision + fresh-state stores (invisible to wave1: nothing
        // links to j/bb until phase2)
        int dtr0 = f_tr(recd, 0);
        int dtr1 = f_tr(recd, 1);
        const unsigned fmdhi = (unsigned)(recd >> 32);  // fl|ml of d
        if (!nobrk) {
          const int mld = (int)(fmdhi >> 16);
          if (mlp + 1 == mld) {
            flj = d;
          } else {
            bb = u++;  // clone of d with length mlp+1
            // patch phase2 prefix-store effect on tk[d] (d may be pre-t2 node)
            const u64m pb = __ballot(prefl && cid == d);
            if (pb != 0ull) { if (ks) dtr1 = j; else dtr0 = j; }
            if (lane == 0) {
              // rl[bb] copy elided: bb is slot 1 of new chain -> stamped i
              reca[bb] = (u64m)(unsigned short)dtr0
                       | ((u64m)(unsigned short)dtr1 << 16)
                       | ((u64m)(fmdhi & 0xFFFFu) << 32)
                       | ((u64m)(unsigned)(mlp + 1) << 48);
            }
            flj = bb;
          }
        }
        if (lane == 0)
          rech[2 * j + 1] = (unsigned)(flj & 0xFFFF) | ((unsigned)mlj << 16);

        if (bb >= 0) {  // redirect run: contiguous img==d from t2
          const u64m eq = __ballot(cval && img == d) >> t2;
          const int runlen = (eq == ~0ull) ? 64 : (int)__builtin_ctzll(~eq);
          inrun = cval && lane >= t2 && lane < t2 + runlen;
        }
      }
    } else {
      // ================= PHASE 1 — QUERY (reads only; sees post-(i-1)) ====
      const int qs = sym;
      int p, x;
      u64m recP; int rlv;

      // speculative first hop: verify load + spec hop-2 loads issued together
      const u64m fresh = reca[w];            // authoritative reca[w]
      const int tvs = f_tr(rrP, qs);         // spec transition from cached rec
      const int ps = (tvs != -1) ? tvs : 0;
      const u64m rr2 = reca[ps];             // spec hop-2 record
      const int rl2 = (int)(short)rla[ps];   // spec hop-2 rla
      if (fresh == rrP && tvs != -1) {
        // spec hit: both hops resolved with one round of latency
        p = tvs; x = h + 1; recP = rr2; rlv = rl2;
      } else {
        // generic walk1 from the fresh (authoritative) record
        u64m rr = fresh; p = w; x = h;
        for (;;) {
          const int tv = f_tr(rr, qs);
          if (tv != -1) { p = tv; x = x + 1; break; }
          const int mp = f_ml(rr);
          if (x > mp) x = mp;
          p = f_fl(rr);
          if (p == -1) { p = 0; x = 0; break; }
          rr = reca[p];   // ONE b64 per hop
        }
        recP = reca[p]; rlv = (int)(short)rla[p];
      }

      unsigned fmv = (unsigned)(recP >> 32);
      int vst = p;
      for (;;) {
        const int fv = (int)(short)(fmv & 0xFFFFu);
        if (fv == -1) break;
        const unsigned fmf = rech[2 * fv + 1];
        const int rlf = (int)(short)rla[fv];   // speculative, same hop
        if ((int)(fmf >> 16) < x) break;
        vst = fv; fmv = fmf; rlv = rlf;
      }
      int rv = -1;
      for (;;) {
        if (vst == -1) { rv = -1; break; }
        if ((int)(fmv >> 16) > 0 && rlv >= 0) { rv = rlv; break; }
        vst = (int)(short)(fmv & 0xFFFFu);
        if (vst == -1) { rv = -1; break; }
        fmv = rech[2 * vst + 1];
        rlv = (int)(short)rla[vst];
      }
      w = p; h = x;
      rrP = recP;   // cache reca[p] for the next query's speculation
      if (lane == 0) outr[(size_t)i * C] = (unsigned)(rv + 1);
    }

    asm volatile("" ::: "memory");
    __builtin_amdgcn_s_barrier();   // ---- A: query reads done ----
    asm volatile("" ::: "memory");

    if (wid == 0) {
      // ============ PHASE 2 — KEY visible stores (exclusive) ==============
      const int ks = sym;
      if (hot) {
        if (prefl) recw[4 * cid + ks] = (unsigned short)j;
        if (inrun) recw[4 * cid + ks] = (unsigned short)bb;
        if (bb >= 0 && lane == 0) recw[4 * d + 2] = (unsigned short)bb; // fl[d]=bb

        // new chain: [j, flj, run-start images #1.., root]
        int nv = 0;  // default root/padding (safe gather next step)
        if (lane == 0) nv = j;
        else if (lane == 1) nv = flj;
        else if (lane - 1 < ndd) nv = pushed;
        const bool nval = (lane < newlen);
        if (nval) rla[nv] = (unsigned short)i;

        const bool overflow = (newlen > 64);
        if (overflow) {  // cold: stamp the unstored tail serially
          const int nv63 = __builtin_amdgcn_readlane(nv, 63);
          if (lane == 0) {
            int vp = (int)(short)(rech[2 * nv63 + 1] & 0xFFFFu);
            while (vp != -1) {
              rla[vp] = (unsigned short)i;
              vp = (int)(short)(rech[2 * vp + 1] & 0xFFFFu);
            }
          }
        }
        cid = nv; cval = nval; trunc = overflow;
      } else {
        // ===== COLD fallback: reference-exact serial step (R10-verified) ==
        int pcur = g, d2 = -1, idbrk = -1;
        for (;;) {
          if (pcur == -1) break;
          const u64m rr = reca[pcur];
          const int tv = f_tr(rr, ks);
          if (tv != -1) { d2 = tv; idbrk = pcur; break; }
          if (lane == 0) recw[4 * pcur + ks] = (unsigned short)j;
          pcur = f_fl(rr);
        }
        int fl2 = 0;
        if (d2 != -1) {
          const int mlp2 = f_ml(reca[idbrk]);
          const u64m rd2 = reca[d2];
          const int mld = f_ml(rd2);
          if (mlp2 + 1 == mld) {
            fl2 = d2;
          } else {
            const int bbc = u++;
            const int drl = (int)(short)rla[d2];
            if (lane == 0) {
              reca[bbc] = (u64m)(unsigned short)f_tr(rd2, 0)
                        | ((u64m)(unsigned short)f_tr(rd2, 1) << 16)
                        | ((u64m)((unsigned)(rd2 >> 32) & 0xFFFFu) << 32)
                        | ((u64m)(unsigned)(mlp2 + 1) << 48);
              rla[bbc] = (unsigned short)drl;
              recw[4 * d2 + 2] = (unsigned short)bbc;   // fl[d2] = bbc
            }
            fl2 = bbc;
            int p3 = idbrk;
            for (;;) {
              if (p3 == -1) break;
              const u64m r3 = reca[p3];
              const int tv3 = f_tr(r3, ks);
              if (tv3 != d2) break;
              if (lane == 0) recw[4 * p3 + ks] = (unsigned short)bbc;
              p3 = f_fl(r3);
            }
          }
        }
        if (lane == 0)
          rech[2 * j + 1] = (unsigned)(fl2 & 0xFFFF) | ((unsigned)mlj << 16);
        // full propagation walk; rebuild lane chain while stamping
        int vp = j, ncs = 0;
        bool tr2 = false;
        for (;;) {
          if (vp == -1) break;
          if (ncs < 64) { if (lane == ncs) cid = vp; ++ncs; }
          else tr2 = true;
          if (lane == 0) rla[vp] = (unsigned short)i;
          vp = (int)(short)(rech[2 * vp + 1] & 0xFFFFu);
        }
        cval = (lane < ncs);
        trunc = tr2;
      }
      g = j; mlg = mlj;
    }
    // wave1: nothing in phase2.

    // next-step symbol (both waves, own stream)
    if (i + 1 < T) {
      const int in = i + 1;
      const unsigned bw = (unsigned)__builtin_amdgcn_readlane((int)bits, in >> 5);
      sym = (int)((bw >> (in & 31)) & 1u);
    }

    // drain wave0's LDS stores so wave1's next-phase1 reads see them; raw
    // barrier (no vmcnt drain: wave1's outr store stays in flight).
    asm volatile("s_waitcnt lgkmcnt(0)" ::: "memory");
    __builtin_amdgcn_s_barrier();   // ---- B: automaton post-i published ----
    asm volatile("" ::: "memory");
  }
}

// Fully parallel epilogue: vidx (u32, = r+1, 0 = no match) -> sign*e.
__global__ __launch_bounds__(256)
void samx_epilogue(const float* __restrict__ v,
                   const float* __restrict__ e,
                   unsigned* __restrict__ out,
                   int T, int C, int total) {
  const int idx = blockIdx.x * 256 + threadIdx.x;
  if (idx >= total) return;
  const unsigned vidx = out[idx];
  const int c = idx % C;
  const int bi = idx / C;
  const int b = bi / T;
  const float ev = e[c];
  float val = -ev;  // y=0
  if (vidx != 0u) {
    if (v[((size_t)b * (size_t)T + (size_t)vidx) * (size_t)C + (size_t)c] > 0.0f)
      val = ev;
  }
  out[idx] = __float_as_uint(val);
}

extern "C" void kernel_launch(void* const* d_in, const int* in_sizes, int n_in,
                              void* d_out, int out_size, void* d_ws, size_t ws_size,
                              hipStream_t stream) {
  const float* q = (const float*)d_in[0];
  const float* k = (const float*)d_in[1];
  const float* v = (const float*)d_in[2];
  const float* e = (const float*)d_in[3];

  const int C = in_sizes[3];
  const int T = TLEN;
  const int B = in_sizes[0] / (T * C);
  const int total = out_size;

  samx_main<<<dim3(B * C), dim3(128), 0, stream>>>(q, k, (unsigned*)d_out, T, C);
  samx_epilogue<<<dim3((total + 255) / 256), dim3(256), 0, stream>>>(
      v, e, (unsigned*)d_out, T, C, total);
}